// Round 8
// baseline (220.010 us; speedup 1.0000x reference)
//
#include <hip/hip_runtime.h>
#include <hip/hip_bf16.h>
#include <stdint.h>

#define B_   64
#define L_   512
#define E_   256
#define P_   64
#define KOUT 512
#define KS_  3
#define H_   512
#define T_   53
#define CINW 2688           // conv_w inner: 896*3
#define LE   516            // embp rows/batch: L + 4 (2 zero each side)
#define LPP  514            // posp rows/batch: L + 2 (1 zero each side)
#define COMW 2048           // 1536 ent + 512 sent_h

// prep-kernel grid sections
#define SEC_CW    0
#define SEC_EMBP  512
#define SEC_POSP  (SEC_EMBP + (B_ * LE / 4))     // 512 + 8256 = 8768
#define SEC_ENT   (SEC_POSP + (B_ * LPP / 4))    // 8768 + 8224 = 16992
#define SEC_POOL  (SEC_ENT + 2 * B_)             // 16992 + 128 = 17120
#define SEC_CORR  (SEC_POOL + 32)                // 17152
#define SEC_END   (SEC_CORR + 4096)              // 21248

typedef __attribute__((ext_vector_type(8))) short bf16x8;
typedef __attribute__((ext_vector_type(4))) float f32x4;

__device__ __forceinline__ unsigned enc_f(float x) {
    unsigned u = __float_as_uint(x);
    return (u & 0x80000000u) ? ~u : (u | 0x80000000u);
}
__device__ __forceinline__ float dec_f(unsigned e) {
    return __uint_as_float((e & 0x80000000u) ? (e & 0x7fffffffu) : ~e);
}

__device__ __forceinline__ void cp16(const void* g, void* l) {
    __builtin_amdgcn_global_load_lds(
        (const __attribute__((address_space(1))) unsigned int*)g,
        (__attribute__((address_space(3))) unsigned int*)l,
        16, 0, 0);
}

// ---------------------------------------------------------------------------
// Fused prep: 6 independent jobs selected by blockIdx.x section.
//  [0,512):          combine_w  -> wce/wcp
//  [512,8768):       build_embp
//  [8768,16992):     build_posp
//  [16992,17120):    entity_feats -> com[:,0:1536)
//  [17120,17152):    zero pooled
//  [17152,21248):    corr (edge-correction dots, direct from conv_w)
__global__ void prep(const float* __restrict__ conv_w,
                     const int* __restrict__ context,
                     const int* __restrict__ sidx,
                     const int* __restrict__ oidx,
                     const int* __restrict__ sdis,
                     const int* __restrict__ odis,
                     const float* __restrict__ etab,
                     const float* __restrict__ ptab,
                     __hip_bfloat16* __restrict__ wce,
                     __hip_bfloat16* __restrict__ wcp,
                     __hip_bfloat16* __restrict__ embp,
                     __hip_bfloat16* __restrict__ posp,
                     float* __restrict__ com,
                     unsigned* __restrict__ pooled,
                     float* __restrict__ corr) {
    __shared__ float w[CINW];           // used by combine_w section only
    const int blk = blockIdx.x;
    const int tid = threadIdx.x;

    if (blk < SEC_EMBP) {
        // ---- combine_w: one block per output channel n ----
        int n = blk;
        const float* src = conv_w + (size_t)n * CINW;
        for (int i = tid; i < CINW; i += 256) w[i] = src[i];
        __syncthreads();
        for (int i = tid; i < 5 * E_; i += 256) {
            int d = i >> 8, c = i & 255;
            float s = 0.f;
#pragma unroll
            for (int tau = 0; tau <= 2; tau++) {
                int seg = d - tau;
                if (seg >= 0 && seg <= 2) s += w[(seg * 256 + c) * 3 + tau];
            }
            wce[((size_t)d * KOUT + n) * E_ + c] = __float2bfloat16(s);
        }
        for (int i = tid; i < 3 * 128; i += 256) {
            int tau = i >> 7, p = i & 127;
            wcp[((size_t)tau * KOUT + n) * 128 + p] = __float2bfloat16(w[(768 + p) * 3 + tau]);
        }
    } else if (blk < SEC_POSP) {
        // ---- build_embp ----
        int row = (blk - SEC_EMBP) * 4 + (tid >> 6);
        int lane = tid & 63;
        int b = row / LE, r = row % LE;
        __hip_bfloat16* out = embp + (size_t)row * E_;
        if (r < 2 || r >= LE - 2) {
            *(ushort4*)(out + lane * 4) = (ushort4){0, 0, 0, 0};
            return;
        }
        int token = context[b * L_ + (r - 2)];
        float4 v = *(const float4*)(etab + (size_t)token * E_ + lane * 4);
        union { __hip_bfloat16 h[4]; ushort4 u; } pk;
        pk.h[0] = __float2bfloat16(v.x); pk.h[1] = __float2bfloat16(v.y);
        pk.h[2] = __float2bfloat16(v.z); pk.h[3] = __float2bfloat16(v.w);
        *(ushort4*)(out + lane * 4) = pk.u;
    } else if (blk < SEC_ENT) {
        // ---- build_posp ----
        int row = (blk - SEC_POSP) * 4 + (tid >> 6);
        int lane = tid & 63;
        int b = row / LPP, r = row % LPP;
        __hip_bfloat16* out = posp + (size_t)row * 128;
        if (r < 1 || r >= LPP - 1) {
            *(unsigned*)(out + lane * 2) = 0u;
            return;
        }
        int l = r - 1;
        int which = lane >> 5;
        int i2 = (lane & 31) * 2;
        int t = which ? odis[b * L_ + l] : sdis[b * L_ + l];
        float2 v = *(const float2*)(ptab + (size_t)t * P_ + i2);
        union { __hip_bfloat16 h[2]; unsigned u; } pk;
        pk.h[0] = __float2bfloat16(v.x); pk.h[1] = __float2bfloat16(v.y);
        *(unsigned*)(out + which * 64 + i2) = pk.u;
    } else if (blk < SEC_POOL) {
        // ---- entity_feats ----
        int idx = blk - SEC_ENT;
        int b = idx >> 1, which = idx & 1;
        const int* sp = which ? oidx : sidx;
        int s = sp[b * 2 + 0], e = sp[b * 2 + 1];
        const int* ctx = context + b * L_;
        float* outb = com + (size_t)b * COMW + which * 768;
        int d = tid;
        float sum = 0.f;
        for (int x = s; x <= e; ++x) sum += etab[(size_t)ctx[x] * E_ + d];
        outb[d] = sum / (float)(e - s + 1);
        outb[256 + d] = etab[(size_t)ctx[s - 1] * E_ + d];
        float r = 0.f;
        if (e + 1 < L_) r = etab[(size_t)ctx[e + 1] * E_ + d];
        outb[512 + d] = r;
    } else if (blk < SEC_CORR) {
        // ---- zero pooled ----
        int base = ((blk - SEC_POOL) * 256 + tid) * 4;
        *(uint4*)(pooled + base) = (uint4){0, 0, 0, 0};
    } else {
        // ---- edge-correction: corr[b][which][n] = emb_edge(b,which).w_slice ----
        // which=0 (l=0 spurious):   w[(512+c)*3 + 0]
        // which=1 (l=511 spurious): w[c*3 + 2]
        int wid = (blk - SEC_CORR) * 4 + (tid >> 6);   // 0..16383
        int lane = tid & 63;
        int n4    = wid & 127;
        int which = (wid >> 7) & 1;
        int b     = wid >> 8;
        int token = context[b * L_ + (which ? L_ - 1 : 0)];
        float4 ev = *(const float4*)(etab + (size_t)token * E_ + lane * 4);
#pragma unroll
        for (int k = 0; k < 4; k++) {
            int n = n4 * 4 + k;
            const float* base = conv_w + (size_t)n * CINW;
            int c0 = lane * 4;
            float s;
            if (which) {
                s = ev.x * base[(c0 + 0) * 3 + 2] + ev.y * base[(c0 + 1) * 3 + 2]
                  + ev.z * base[(c0 + 2) * 3 + 2] + ev.w * base[(c0 + 3) * 3 + 2];
            } else {
                s = ev.x * base[(512 + c0 + 0) * 3] + ev.y * base[(512 + c0 + 1) * 3]
                  + ev.z * base[(512 + c0 + 2) * 3] + ev.w * base[(512 + c0 + 3) * 3];
            }
#pragma unroll
            for (int off = 32; off > 0; off >>= 1) s += __shfl_down(s, off, 64);
            if (lane == 0) corr[(b * 2 + which) * KOUT + n] = s;
        }
    }
}

// ---------------------------------------------------------------------------
// conv as 5 emb-taps + 3 pos-taps GEMM (bf16 MFMA), fused maxpool + edge corr.
// R5 structure: 16 KB LDS, per-tap staging, 3 blocks/CU. This is the measured
// sweet spot — R7's 52 KB tap-shift variant lost the occupancy it gained in
// barriers (34%->21% occ, net neutral). Do not enlarge LDS here.
__global__ void conv_gemm_pool(const __hip_bfloat16* __restrict__ embp,
                               const __hip_bfloat16* __restrict__ posp,
                               const __hip_bfloat16* __restrict__ wce,
                               const __hip_bfloat16* __restrict__ wcp,
                               const float* __restrict__ corr,
                               unsigned* __restrict__ pooled) {
    __shared__ __hip_bfloat16 sA[128 * 32];
    __shared__ __hip_bfloat16 sB[128 * 32];

    const int tid  = threadIdx.x;
    const int wave = tid >> 6;
    const int lane = tid & 63;
    const int mt = blockIdx.x;
    const int nt = blockIdx.y;
    const int b  = mt >> 2;
    const int l0 = (mt & 3) * 128;
    const int n0 = nt * 128;

    const int wr = (wave & 1) * 64;
    const int wc = (wave >> 1) * 64;
    const int m  = lane & 15;
    const int q  = lane >> 4;

    f32x4 acc[4][4];
#pragma unroll
    for (int i = 0; i < 4; i++)
#pragma unroll
        for (int j = 0; j < 4; j++) acc[i][j] = (f32x4){0.f, 0.f, 0.f, 0.f};

    const int rowA = tid >> 2;
    const int cswz = (((tid & 3) ^ ((tid >> 3) & 3))) * 16;
    const int rsw  = (q ^ ((m >> 1) & 3)) * 16;

    auto step = [&](const char* Ab, int AsB, const char* Bb, int BsB) {
        cp16(Ab + rowA * AsB + cswz, (char*)sA + tid * 16);
        cp16(Bb + rowA * BsB + cswz, (char*)sB + tid * 16);
        cp16(Ab + (rowA + 64) * AsB + cswz, (char*)sA + (tid + 256) * 16);
        cp16(Bb + (rowA + 64) * BsB + cswz, (char*)sB + (tid + 256) * 16);
        __syncthreads();
        bf16x8 af[4], bfr[4];
#pragma unroll
        for (int i = 0; i < 4; i++)
            af[i] = *(const bf16x8*)((const char*)sA + (wr + i * 16 + m) * 64 + rsw);
#pragma unroll
        for (int j = 0; j < 4; j++)
            bfr[j] = *(const bf16x8*)((const char*)sB + (wc + j * 16 + m) * 64 + rsw);
#pragma unroll
        for (int i = 0; i < 4; i++)
#pragma unroll
            for (int j = 0; j < 4; j++)
                acc[i][j] = __builtin_amdgcn_mfma_f32_16x16x32_bf16(
                    af[i], bfr[j], acc[i][j], 0, 0, 0);
        __syncthreads();
    };

    for (int t = 0; t < 5; t++) {
        const char* Abase = (const char*)(embp + (size_t)(b * LE + l0 + t) * E_);
        const char* Bbase = (const char*)(wce + (size_t)(t * KOUT + n0) * E_);
        for (int kc = 0; kc < E_; kc += 32)
            step(Abase + kc * 2, E_ * 2, Bbase + kc * 2, E_ * 2);
    }
    for (int t = 0; t < 3; t++) {
        const char* Abase = (const char*)(posp + (size_t)(b * LPP + l0 + t) * 128);
        const char* Bbase = (const char*)(wcp + (size_t)(t * KOUT + n0) * 128);
        for (int kc = 0; kc < 128; kc += 32)
            step(Abase + kc * 2, 256, Bbase + kc * 2, 256);
    }

    const float* corrb = corr + b * 2 * KOUT;
#pragma unroll
    for (int j = 0; j < 4; j++) {
        int col = n0 + wc + j * 16 + m;
        float mx = -3.4e38f;
#pragma unroll
        for (int i = 0; i < 4; i++)
#pragma unroll
            for (int r = 0; r < 4; r++) {
                float v = acc[i][j][r];
                int l = l0 + wr + i * 16 + q * 4 + r;
                if (l == 0)      v -= corrb[col];
                if (l == L_ - 1) v -= corrb[KOUT + col];
                mx = fmaxf(mx, v);
            }
        mx = fmaxf(mx, __shfl_xor(mx, 16, 64));
        mx = fmaxf(mx, __shfl_xor(mx, 32, 64));
        if (q == 0) atomicMax(&pooled[b * KOUT + col], enc_f(mx));
    }
}

// ---------------------------------------------------------------------------
__global__ void lin1_k(const unsigned* __restrict__ pooled,
                       const float* __restrict__ conv_b,
                       const float* __restrict__ lin1_w,
                       const float* __restrict__ lin1_b,
                       float* __restrict__ com) {
    int bid = blockIdx.x;
    int wave = threadIdx.x >> 6, lane = threadIdx.x & 63;
    int b = bid >> 7;
    int h = (bid & 127) * 4 + wave;
    const float* w = lin1_w + (size_t)h * KOUT;
    const unsigned* pb = pooled + b * KOUT;
    float s = 0.f;
#pragma unroll
    for (int i = 0; i < 8; i++) {
        int k = lane + 64 * i;
        s += (dec_f(pb[k]) + conv_b[k]) * w[k];
    }
#pragma unroll
    for (int off = 32; off > 0; off >>= 1) s += __shfl_down(s, off, 64);
    if (lane == 0) com[(size_t)b * COMW + 1536 + h] = tanhf(s + lin1_b[h]);
}

__global__ void lin2_k(const float* __restrict__ com,
                       const float* __restrict__ lin2_w,
                       const float* __restrict__ lin2_b,
                       float* __restrict__ out) {
    int b = blockIdx.x;
    int wave = threadIdx.x >> 6, lane = threadIdx.x & 63;
    int t = blockIdx.y * 4 + wave;
    if (t >= T_) return;
    const float* w = lin2_w + (size_t)t * COMW;
    const float* c = com + (size_t)b * COMW;
    float s = 0.f;
#pragma unroll
    for (int i = 0; i < 32; i++) {
        int k = lane + 64 * i;
        s += c[k] * w[k];
    }
#pragma unroll
    for (int off = 32; off > 0; off >>= 1) s += __shfl_down(s, off, 64);
    if (lane == 0) out[b * T_ + t] = s + lin2_b[t];
}

// ---------------------------------------------------------------------------
extern "C" void kernel_launch(void* const* d_in, const int* in_sizes, int n_in,
                              void* d_out, int out_size, void* d_ws, size_t ws_size,
                              hipStream_t stream) {
    const int*   context = (const int*)d_in[0];
    const int*   sidx    = (const int*)d_in[1];
    const int*   oidx    = (const int*)d_in[2];
    const int*   sdis    = (const int*)d_in[3];
    const int*   odis    = (const int*)d_in[4];
    const float* etab    = (const float*)d_in[5];
    const float* ptab    = (const float*)d_in[6];
    const float* conv_w  = (const float*)d_in[7];
    const float* conv_b  = (const float*)d_in[8];
    const float* lin1_w  = (const float*)d_in[9];
    const float* lin1_b  = (const float*)d_in[10];
    const float* lin2_w  = (const float*)d_in[11];
    const float* lin2_b  = (const float*)d_in[12];
    float* out = (float*)d_out;

    char* ws = (char*)d_ws;
    size_t off = 0;
    __hip_bfloat16* embp = (__hip_bfloat16*)(ws + off);
    off += (size_t)B_ * LE * E_ * 2;             // 16.9 MB
    off = (off + 255) & ~(size_t)255;
    __hip_bfloat16* posp = (__hip_bfloat16*)(ws + off);
    off += (size_t)B_ * LPP * 128 * 2;           // 8.4 MB
    off = (off + 255) & ~(size_t)255;
    __hip_bfloat16* wce = (__hip_bfloat16*)(ws + off);
    off += (size_t)5 * KOUT * E_ * 2;            // 1.3 MB
    off = (off + 255) & ~(size_t)255;
    __hip_bfloat16* wcp = (__hip_bfloat16*)(ws + off);
    off += (size_t)3 * KOUT * 128 * 2;           // 0.4 MB
    off = (off + 255) & ~(size_t)255;
    float* corr = (float*)(ws + off);
    off += (size_t)B_ * 2 * KOUT * 4;            // 256 KB
    off = (off + 255) & ~(size_t)255;
    unsigned* pooled = (unsigned*)(ws + off);
    off += (size_t)B_ * KOUT * 4;                // 128 KB
    off = (off + 255) & ~(size_t)255;
    float* com = (float*)(ws + off);
    off += (size_t)B_ * COMW * 4;                // 512 KB

    prep<<<dim3(SEC_END), dim3(256), 0, stream>>>(
        conv_w, context, sidx, oidx, sdis, odis, etab, ptab,
        wce, wcp, embp, posp, com, pooled, corr);
    conv_gemm_pool<<<dim3(256, 4), dim3(256), 0, stream>>>(embp, posp, wce, wcp, corr, pooled);
    lin1_k<<<dim3(8192), dim3(256), 0, stream>>>(pooled, conv_b, lin1_w, lin1_b, com);
    lin2_k<<<dim3(B_, 14), dim3(256), 0, stream>>>(com, lin2_w, lin2_b, out);
}

// Round 9
// 218.110 us; speedup vs baseline: 1.0087x; 1.0087x over previous
//
#include <hip/hip_runtime.h>
#include <hip/hip_bf16.h>
#include <stdint.h>

#define B_   64
#define L_   512
#define E_   256
#define P_   64
#define KOUT 512
#define KS_  3
#define H_   512
#define T_   53
#define CINW 2688           // conv_w inner: 896*3
#define LE   516            // embp rows/batch: L + 4 (2 zero each side)
#define LPP  514            // posp rows/batch: L + 2 (1 zero each side)
#define COMW 2048           // 1536 ent + 512 sent_h

// prep-kernel grid sections
#define SEC_CW    0
#define SEC_EMBP  512
#define SEC_POSP  (SEC_EMBP + (B_ * LE / 4))     // 512 + 8256 = 8768
#define SEC_ENT   (SEC_POSP + (B_ * LPP / 4))    // 8768 + 8224 = 16992
#define SEC_POOL  (SEC_ENT + 2 * B_)             // 16992 + 128 = 17120
#define SEC_CORR  (SEC_POOL + 32)                // 17152
#define SEC_END   (SEC_CORR + 4096)              // 21248

typedef __attribute__((ext_vector_type(8))) short bf16x8;
typedef __attribute__((ext_vector_type(4))) float f32x4;

__device__ __forceinline__ unsigned enc_f(float x) {
    unsigned u = __float_as_uint(x);
    return (u & 0x80000000u) ? ~u : (u | 0x80000000u);
}
__device__ __forceinline__ float dec_f(unsigned e) {
    return __uint_as_float((e & 0x80000000u) ? (e & 0x7fffffffu) : ~e);
}

__device__ __forceinline__ void cp16(const void* g, void* l) {
    __builtin_amdgcn_global_load_lds(
        (const __attribute__((address_space(1))) unsigned int*)g,
        (__attribute__((address_space(3))) unsigned int*)l,
        16, 0, 0);
}

// ---------------------------------------------------------------------------
// Fused prep: 6 independent jobs selected by blockIdx.x section.
__global__ void prep(const float* __restrict__ conv_w,
                     const int* __restrict__ context,
                     const int* __restrict__ sidx,
                     const int* __restrict__ oidx,
                     const int* __restrict__ sdis,
                     const int* __restrict__ odis,
                     const float* __restrict__ etab,
                     const float* __restrict__ ptab,
                     __hip_bfloat16* __restrict__ wce,
                     __hip_bfloat16* __restrict__ wcp,
                     __hip_bfloat16* __restrict__ embp,
                     __hip_bfloat16* __restrict__ posp,
                     float* __restrict__ com,
                     unsigned* __restrict__ pooled,
                     float* __restrict__ corr) {
    __shared__ float w[CINW];           // used by combine_w section only
    const int blk = blockIdx.x;
    const int tid = threadIdx.x;

    if (blk < SEC_EMBP) {
        // ---- combine_w: one block per output channel n ----
        int n = blk;
        const float* src = conv_w + (size_t)n * CINW;
        for (int i = tid; i < CINW; i += 256) w[i] = src[i];
        __syncthreads();
        for (int i = tid; i < 5 * E_; i += 256) {
            int d = i >> 8, c = i & 255;
            float s = 0.f;
#pragma unroll
            for (int tau = 0; tau <= 2; tau++) {
                int seg = d - tau;
                if (seg >= 0 && seg <= 2) s += w[(seg * 256 + c) * 3 + tau];
            }
            wce[((size_t)d * KOUT + n) * E_ + c] = __float2bfloat16(s);
        }
        for (int i = tid; i < 3 * 128; i += 256) {
            int tau = i >> 7, p = i & 127;
            wcp[((size_t)tau * KOUT + n) * 128 + p] = __float2bfloat16(w[(768 + p) * 3 + tau]);
        }
    } else if (blk < SEC_POSP) {
        // ---- build_embp ----
        int row = (blk - SEC_EMBP) * 4 + (tid >> 6);
        int lane = tid & 63;
        int b = row / LE, r = row % LE;
        __hip_bfloat16* out = embp + (size_t)row * E_;
        if (r < 2 || r >= LE - 2) {
            *(ushort4*)(out + lane * 4) = (ushort4){0, 0, 0, 0};
            return;
        }
        int token = context[b * L_ + (r - 2)];
        float4 v = *(const float4*)(etab + (size_t)token * E_ + lane * 4);
        union { __hip_bfloat16 h[4]; ushort4 u; } pk;
        pk.h[0] = __float2bfloat16(v.x); pk.h[1] = __float2bfloat16(v.y);
        pk.h[2] = __float2bfloat16(v.z); pk.h[3] = __float2bfloat16(v.w);
        *(ushort4*)(out + lane * 4) = pk.u;
    } else if (blk < SEC_ENT) {
        // ---- build_posp ----
        int row = (blk - SEC_POSP) * 4 + (tid >> 6);
        int lane = tid & 63;
        int b = row / LPP, r = row % LPP;
        __hip_bfloat16* out = posp + (size_t)row * 128;
        if (r < 1 || r >= LPP - 1) {
            *(unsigned*)(out + lane * 2) = 0u;
            return;
        }
        int l = r - 1;
        int which = lane >> 5;
        int i2 = (lane & 31) * 2;
        int t = which ? odis[b * L_ + l] : sdis[b * L_ + l];
        float2 v = *(const float2*)(ptab + (size_t)t * P_ + i2);
        union { __hip_bfloat16 h[2]; unsigned u; } pk;
        pk.h[0] = __float2bfloat16(v.x); pk.h[1] = __float2bfloat16(v.y);
        *(unsigned*)(out + which * 64 + i2) = pk.u;
    } else if (blk < SEC_POOL) {
        // ---- entity_feats ----
        int idx = blk - SEC_ENT;
        int b = idx >> 1, which = idx & 1;
        const int* sp = which ? oidx : sidx;
        int s = sp[b * 2 + 0], e = sp[b * 2 + 1];
        const int* ctx = context + b * L_;
        float* outb = com + (size_t)b * COMW + which * 768;
        int d = tid;
        float sum = 0.f;
        for (int x = s; x <= e; ++x) sum += etab[(size_t)ctx[x] * E_ + d];
        outb[d] = sum / (float)(e - s + 1);
        outb[256 + d] = etab[(size_t)ctx[s - 1] * E_ + d];
        float r = 0.f;
        if (e + 1 < L_) r = etab[(size_t)ctx[e + 1] * E_ + d];
        outb[512 + d] = r;
    } else if (blk < SEC_CORR) {
        // ---- zero pooled ----
        int base = ((blk - SEC_POOL) * 256 + tid) * 4;
        *(uint4*)(pooled + base) = (uint4){0, 0, 0, 0};
    } else {
        // ---- edge-correction: corr[b][which][n] = emb_edge(b,which).w_slice ----
        int wid = (blk - SEC_CORR) * 4 + (tid >> 6);   // 0..16383
        int lane = tid & 63;
        int n4    = wid & 127;
        int which = (wid >> 7) & 1;
        int b     = wid >> 8;
        int token = context[b * L_ + (which ? L_ - 1 : 0)];
        float4 ev = *(const float4*)(etab + (size_t)token * E_ + lane * 4);
#pragma unroll
        for (int k = 0; k < 4; k++) {
            int n = n4 * 4 + k;
            const float* base = conv_w + (size_t)n * CINW;
            int c0 = lane * 4;
            float s;
            if (which) {
                s = ev.x * base[(c0 + 0) * 3 + 2] + ev.y * base[(c0 + 1) * 3 + 2]
                  + ev.z * base[(c0 + 2) * 3 + 2] + ev.w * base[(c0 + 3) * 3 + 2];
            } else {
                s = ev.x * base[(512 + c0 + 0) * 3] + ev.y * base[(512 + c0 + 1) * 3]
                  + ev.z * base[(512 + c0 + 2) * 3] + ev.w * base[(512 + c0 + 3) * 3];
            }
#pragma unroll
            for (int off = 32; off > 0; off >>= 1) s += __shfl_down(s, off, 64);
            if (lane == 0) corr[(b * 2 + which) * KOUT + n] = s;
        }
    }
}

// ---------------------------------------------------------------------------
// conv GEMM, BK=64 via two proven 8KB sub-panels per buffer: same per-32-col
// LDS layout/swizzle as the 0-conflict R5 kernel, but two K-chunks staged per
// barrier pair -> 32 MFMA between barriers (52 barriers vs 104). LDS 32KB
// allows 5 blocks/CU >= the grid limit of 4, so occupancy is preserved
// (R7 lesson: never trade occupancy for barriers here).
__global__ void conv_gemm_pool(const __hip_bfloat16* __restrict__ embp,
                               const __hip_bfloat16* __restrict__ posp,
                               const __hip_bfloat16* __restrict__ wce,
                               const __hip_bfloat16* __restrict__ wcp,
                               const float* __restrict__ corr,
                               unsigned* __restrict__ pooled) {
    __shared__ __hip_bfloat16 sA[2][128 * 32];   // 2 x 8 KB
    __shared__ __hip_bfloat16 sB[2][128 * 32];   // 2 x 8 KB

    const int tid  = threadIdx.x;
    const int wave = tid >> 6;
    const int lane = tid & 63;
    const int mt = blockIdx.x;
    const int nt = blockIdx.y;
    const int b  = mt >> 2;
    const int l0 = (mt & 3) * 128;
    const int n0 = nt * 128;

    const int wr = (wave & 1) * 64;
    const int wc = (wave >> 1) * 64;
    const int m  = lane & 15;
    const int q  = lane >> 4;

    f32x4 acc[4][4];
#pragma unroll
    for (int i = 0; i < 4; i++)
#pragma unroll
        for (int j = 0; j < 4; j++) acc[i][j] = (f32x4){0.f, 0.f, 0.f, 0.f};

    const int rowA = tid >> 2;
    const int cswz = (((tid & 3) ^ ((tid >> 3) & 3))) * 16;
    const int rsw  = (q ^ ((m >> 1) & 3)) * 16;

    // stage one 128x32 sub-panel pair into half h (columns at byte offset koff)
    auto stage = [&](const char* Ab, int AsB, const char* Bb, int BsB, int h) {
        cp16(Ab + rowA * AsB + cswz, (char*)sA[h] + tid * 16);
        cp16(Bb + rowA * BsB + cswz, (char*)sB[h] + tid * 16);
        cp16(Ab + (rowA + 64) * AsB + cswz, (char*)sA[h] + (tid + 256) * 16);
        cp16(Bb + (rowA + 64) * BsB + cswz, (char*)sB[h] + (tid + 256) * 16);
    };
    auto compute = [&](int h) {
        bf16x8 af[4], bfr[4];
#pragma unroll
        for (int i = 0; i < 4; i++)
            af[i] = *(const bf16x8*)((const char*)sA[h] + (wr + i * 16 + m) * 64 + rsw);
#pragma unroll
        for (int j = 0; j < 4; j++)
            bfr[j] = *(const bf16x8*)((const char*)sB[h] + (wc + j * 16 + m) * 64 + rsw);
#pragma unroll
        for (int i = 0; i < 4; i++)
#pragma unroll
            for (int j = 0; j < 4; j++)
                acc[i][j] = __builtin_amdgcn_mfma_f32_16x16x32_bf16(
                    af[i], bfr[j], acc[i][j], 0, 0, 0);
    };

    // emb phase: 5 taps x 4 double-chunks (BK=64)
    for (int t = 0; t < 5; t++) {
        const char* Abase = (const char*)(embp + (size_t)(b * LE + l0 + t) * E_);
        const char* Bbase = (const char*)(wce + (size_t)(t * KOUT + n0) * E_);
        for (int kc = 0; kc < E_; kc += 64) {
            stage(Abase + kc * 2, E_ * 2, Bbase + kc * 2, E_ * 2, 0);
            stage(Abase + kc * 2 + 64, E_ * 2, Bbase + kc * 2 + 64, E_ * 2, 1);
            __syncthreads();
            compute(0);
            compute(1);
            __syncthreads();
        }
    }
    // pos phase: 3 taps x 2 double-chunks
    for (int t = 0; t < 3; t++) {
        const char* Abase = (const char*)(posp + (size_t)(b * LPP + l0 + t) * 128);
        const char* Bbase = (const char*)(wcp + (size_t)(t * KOUT + n0) * 128);
        for (int kc = 0; kc < 128; kc += 64) {
            stage(Abase + kc * 2, 256, Bbase + kc * 2, 256, 0);
            stage(Abase + kc * 2 + 64, 256, Bbase + kc * 2 + 64, 256, 1);
            __syncthreads();
            compute(0);
            compute(1);
            __syncthreads();
        }
    }

    const float* corrb = corr + b * 2 * KOUT;
#pragma unroll
    for (int j = 0; j < 4; j++) {
        int col = n0 + wc + j * 16 + m;
        float mx = -3.4e38f;
#pragma unroll
        for (int i = 0; i < 4; i++)
#pragma unroll
            for (int r = 0; r < 4; r++) {
                float v = acc[i][j][r];
                int l = l0 + wr + i * 16 + q * 4 + r;
                if (l == 0)      v -= corrb[col];
                if (l == L_ - 1) v -= corrb[KOUT + col];
                mx = fmaxf(mx, v);
            }
        mx = fmaxf(mx, __shfl_xor(mx, 16, 64));
        mx = fmaxf(mx, __shfl_xor(mx, 32, 64));
        if (q == 0) atomicMax(&pooled[b * KOUT + col], enc_f(mx));
    }
}

// ---------------------------------------------------------------------------
__global__ void lin1_k(const unsigned* __restrict__ pooled,
                       const float* __restrict__ conv_b,
                       const float* __restrict__ lin1_w,
                       const float* __restrict__ lin1_b,
                       float* __restrict__ com) {
    int bid = blockIdx.x;
    int wave = threadIdx.x >> 6, lane = threadIdx.x & 63;
    int b = bid >> 7;
    int h = (bid & 127) * 4 + wave;
    const float* w = lin1_w + (size_t)h * KOUT;
    const unsigned* pb = pooled + b * KOUT;
    float s = 0.f;
#pragma unroll
    for (int i = 0; i < 8; i++) {
        int k = lane + 64 * i;
        s += (dec_f(pb[k]) + conv_b[k]) * w[k];
    }
#pragma unroll
    for (int off = 32; off > 0; off >>= 1) s += __shfl_down(s, off, 64);
    if (lane == 0) com[(size_t)b * COMW + 1536 + h] = tanhf(s + lin1_b[h]);
}

__global__ void lin2_k(const float* __restrict__ com,
                       const float* __restrict__ lin2_w,
                       const float* __restrict__ lin2_b,
                       float* __restrict__ out) {
    int b = blockIdx.x;
    int wave = threadIdx.x >> 6, lane = threadIdx.x & 63;
    int t = blockIdx.y * 4 + wave;
    if (t >= T_) return;
    const float* w = lin2_w + (size_t)t * COMW;
    const float* c = com + (size_t)b * COMW;
    float s = 0.f;
#pragma unroll
    for (int i = 0; i < 32; i++) {
        int k = lane + 64 * i;
        s += c[k] * w[k];
    }
#pragma unroll
    for (int off = 32; off > 0; off >>= 1) s += __shfl_down(s, off, 64);
    if (lane == 0) out[b * T_ + t] = s + lin2_b[t];
}

// ---------------------------------------------------------------------------
extern "C" void kernel_launch(void* const* d_in, const int* in_sizes, int n_in,
                              void* d_out, int out_size, void* d_ws, size_t ws_size,
                              hipStream_t stream) {
    const int*   context = (const int*)d_in[0];
    const int*   sidx    = (const int*)d_in[1];
    const int*   oidx    = (const int*)d_in[2];
    const int*   sdis    = (const int*)d_in[3];
    const int*   odis    = (const int*)d_in[4];
    const float* etab    = (const float*)d_in[5];
    const float* ptab    = (const float*)d_in[6];
    const float* conv_w  = (const float*)d_in[7];
    const float* conv_b  = (const float*)d_in[8];
    const float* lin1_w  = (const float*)d_in[9];
    const float* lin1_b  = (const float*)d_in[10];
    const float* lin2_w  = (const float*)d_in[11];
    const float* lin2_b  = (const float*)d_in[12];
    float* out = (float*)d_out;

    char* ws = (char*)d_ws;
    size_t off = 0;
    __hip_bfloat16* embp = (__hip_bfloat16*)(ws + off);
    off += (size_t)B_ * LE * E_ * 2;             // 16.9 MB
    off = (off + 255) & ~(size_t)255;
    __hip_bfloat16* posp = (__hip_bfloat16*)(ws + off);
    off += (size_t)B_ * LPP * 128 * 2;           // 8.4 MB
    off = (off + 255) & ~(size_t)255;
    __hip_bfloat16* wce = (__hip_bfloat16*)(ws + off);
    off += (size_t)5 * KOUT * E_ * 2;            // 1.3 MB
    off = (off + 255) & ~(size_t)255;
    __hip_bfloat16* wcp = (__hip_bfloat16*)(ws + off);
    off += (size_t)3 * KOUT * 128 * 2;           // 0.4 MB
    off = (off + 255) & ~(size_t)255;
    float* corr = (float*)(ws + off);
    off += (size_t)B_ * 2 * KOUT * 4;            // 256 KB
    off = (off + 255) & ~(size_t)255;
    unsigned* pooled = (unsigned*)(ws + off);
    off += (size_t)B_ * KOUT * 4;                // 128 KB
    off = (off + 255) & ~(size_t)255;
    float* com = (float*)(ws + off);
    off += (size_t)B_ * COMW * 4;                // 512 KB

    prep<<<dim3(SEC_END), dim3(256), 0, stream>>>(
        conv_w, context, sidx, oidx, sdis, odis, etab, ptab,
        wce, wcp, embp, posp, com, pooled, corr);
    conv_gemm_pool<<<dim3(256, 4), dim3(256), 0, stream>>>(embp, posp, wce, wcp, corr, pooled);
    lin1_k<<<dim3(8192), dim3(256), 0, stream>>>(pooled, conv_b, lin1_w, lin1_b, com);
    lin2_k<<<dim3(B_, 14), dim3(256), 0, stream>>>(com, lin2_w, lin2_b, out);
}

// Round 10
// 213.816 us; speedup vs baseline: 1.0290x; 1.0201x over previous
//
#include <hip/hip_runtime.h>
#include <hip/hip_bf16.h>
#include <stdint.h>

#define B_   64
#define L_   512
#define E_   256
#define P_   64
#define KOUT 512
#define KS_  3
#define H_   512
#define T_   53
#define CINW 2688           // conv_w inner: 896*3
#define LE   516            // embp rows/batch: L + 4 (2 zero each side)
#define LPP  514            // posp rows/batch: L + 2 (1 zero each side)
#define COMW 2048           // 1536 ent + 512 sent_h

// prep-kernel grid sections (R7 layout: corr is a separate kernel)
#define SEC_CW    0
#define SEC_EMBP  512
#define SEC_POSP  (SEC_EMBP + (B_ * LE / 4))     // 512 + 8256 = 8768
#define SEC_ENT   (SEC_POSP + (B_ * LPP / 4))    // 8768 + 8224 = 16992
#define SEC_POOL  (SEC_ENT + 2 * B_)             // 16992 + 128 = 17120
#define SEC_END   (SEC_POOL + 32)                // 17152

typedef __attribute__((ext_vector_type(8))) short bf16x8;
typedef __attribute__((ext_vector_type(4))) float f32x4;

__device__ __forceinline__ unsigned enc_f(float x) {
    unsigned u = __float_as_uint(x);
    return (u & 0x80000000u) ? ~u : (u | 0x80000000u);
}
__device__ __forceinline__ float dec_f(unsigned e) {
    return __uint_as_float((e & 0x80000000u) ? (e & 0x7fffffffu) : ~e);
}

__device__ __forceinline__ void cp16(const void* g, void* l) {
    __builtin_amdgcn_global_load_lds(
        (const __attribute__((address_space(1))) unsigned int*)g,
        (__attribute__((address_space(3))) unsigned int*)l,
        16, 0, 0);
}

// ---------------------------------------------------------------------------
// Fused prep: 5 independent jobs selected by blockIdx.x section.
//  [0,512):        combine_w -> wce/wcp/wcorr
//  [512,8768):     build_embp
//  [8768,16992):   build_posp
//  [16992,17120):  entity_feats -> com[:,0:1536)
//  [17120,17152):  zero pooled
__global__ void prep(const float* __restrict__ conv_w,
                     const int* __restrict__ context,
                     const int* __restrict__ sidx,
                     const int* __restrict__ oidx,
                     const int* __restrict__ sdis,
                     const int* __restrict__ odis,
                     const float* __restrict__ etab,
                     const float* __restrict__ ptab,
                     __hip_bfloat16* __restrict__ wce,
                     __hip_bfloat16* __restrict__ wcp,
                     __hip_bfloat16* __restrict__ wcorr,
                     __hip_bfloat16* __restrict__ embp,
                     __hip_bfloat16* __restrict__ posp,
                     float* __restrict__ com,
                     unsigned* __restrict__ pooled) {
    __shared__ float w[CINW];           // used by combine_w section only
    const int blk = blockIdx.x;
    const int tid = threadIdx.x;

    if (blk < SEC_EMBP) {
        // ---- combine_w: one block per output channel n; conv_w row staged
        // in LDS coalesced once, all derived layouts emitted coalesced ----
        int n = blk;
        const float* src = conv_w + (size_t)n * CINW;
        for (int i = tid; i < CINW; i += 256) w[i] = src[i];
        __syncthreads();
        for (int i = tid; i < 5 * E_; i += 256) {
            int d = i >> 8, c = i & 255;
            float s = 0.f;
#pragma unroll
            for (int tau = 0; tau <= 2; tau++) {
                int seg = d - tau;
                if (seg >= 0 && seg <= 2) s += w[(seg * 256 + c) * 3 + tau];
            }
            wce[((size_t)d * KOUT + n) * E_ + c] = __float2bfloat16(s);
        }
        for (int i = tid; i < 3 * 128; i += 256) {
            int tau = i >> 7, p = i & 127;
            wcp[((size_t)tau * KOUT + n) * 128 + p] = __float2bfloat16(w[(768 + p) * 3 + tau]);
        }
        for (int i = tid; i < 2 * E_; i += 256) {
            int which = i >> 8, c = i & 255;
            wcorr[((size_t)which * KOUT + n) * E_ + c] =
                __float2bfloat16(which ? w[c * 3 + 2] : w[(512 + c) * 3 + 0]);
        }
    } else if (blk < SEC_POSP) {
        // ---- build_embp ----
        int row = (blk - SEC_EMBP) * 4 + (tid >> 6);
        int lane = tid & 63;
        int b = row / LE, r = row % LE;
        __hip_bfloat16* out = embp + (size_t)row * E_;
        if (r < 2 || r >= LE - 2) {
            *(ushort4*)(out + lane * 4) = (ushort4){0, 0, 0, 0};
            return;
        }
        int token = context[b * L_ + (r - 2)];
        float4 v = *(const float4*)(etab + (size_t)token * E_ + lane * 4);
        union { __hip_bfloat16 h[4]; ushort4 u; } pk;
        pk.h[0] = __float2bfloat16(v.x); pk.h[1] = __float2bfloat16(v.y);
        pk.h[2] = __float2bfloat16(v.z); pk.h[3] = __float2bfloat16(v.w);
        *(ushort4*)(out + lane * 4) = pk.u;
    } else if (blk < SEC_ENT) {
        // ---- build_posp ----
        int row = (blk - SEC_POSP) * 4 + (tid >> 6);
        int lane = tid & 63;
        int b = row / LPP, r = row % LPP;
        __hip_bfloat16* out = posp + (size_t)row * 128;
        if (r < 1 || r >= LPP - 1) {
            *(unsigned*)(out + lane * 2) = 0u;
            return;
        }
        int l = r - 1;
        int which = lane >> 5;
        int i2 = (lane & 31) * 2;
        int t = which ? odis[b * L_ + l] : sdis[b * L_ + l];
        float2 v = *(const float2*)(ptab + (size_t)t * P_ + i2);
        union { __hip_bfloat16 h[2]; unsigned u; } pk;
        pk.h[0] = __float2bfloat16(v.x); pk.h[1] = __float2bfloat16(v.y);
        *(unsigned*)(out + which * 64 + i2) = pk.u;
    } else if (blk < SEC_POOL) {
        // ---- entity_feats ----
        int idx = blk - SEC_ENT;
        int b = idx >> 1, which = idx & 1;
        const int* sp = which ? oidx : sidx;
        int s = sp[b * 2 + 0], e = sp[b * 2 + 1];
        const int* ctx = context + b * L_;
        float* outb = com + (size_t)b * COMW + which * 768;
        int d = tid;
        float sum = 0.f;
        for (int x = s; x <= e; ++x) sum += etab[(size_t)ctx[x] * E_ + d];
        outb[d] = sum / (float)(e - s + 1);
        outb[256 + d] = etab[(size_t)ctx[s - 1] * E_ + d];
        float r = 0.f;
        if (e + 1 < L_) r = etab[(size_t)ctx[e + 1] * E_ + d];
        outb[512 + d] = r;
    } else {
        // ---- zero pooled ----
        int base = ((blk - SEC_POOL) * 256 + tid) * 4;
        *(uint4*)(pooled + base) = (uint4){0, 0, 0, 0};
    }
}

// ---------------------------------------------------------------------------
// Edge-correction: corr[b][which][n] = emb_edge(b,which) . wcorr[which][n][:]
// One wave per (b, which, 4-n group); fully coalesced (wcorr is contiguous).
__global__ void corr_k(const int* __restrict__ ctx,
                       const float* __restrict__ etab,
                       const __hip_bfloat16* __restrict__ wcorr,
                       float* __restrict__ corr) {
    int wid = blockIdx.x * 4 + (threadIdx.x >> 6);
    int lane = threadIdx.x & 63;
    int n4    = wid & 127;
    int which = (wid >> 7) & 1;
    int b     = wid >> 8;
    int token = ctx[b * L_ + (which ? L_ - 1 : 0)];
    float4 ev = *(const float4*)(etab + (size_t)token * E_ + lane * 4);
#pragma unroll
    for (int k = 0; k < 4; k++) {
        int n = n4 * 4 + k;
        const __hip_bfloat16* wr = wcorr + ((size_t)which * KOUT + n) * E_ + lane * 4;
        float s = ev.x * __bfloat162float(wr[0]) + ev.y * __bfloat162float(wr[1])
                + ev.z * __bfloat162float(wr[2]) + ev.w * __bfloat162float(wr[3]);
#pragma unroll
        for (int off = 32; off > 0; off >>= 1) s += __shfl_down(s, off, 64);
        if (lane == 0) corr[(b * 2 + which) * KOUT + n] = s;
    }
}

// ---------------------------------------------------------------------------
// conv as 5 emb-taps + 3 pos-taps GEMM (bf16 MFMA), fused maxpool + edge corr.
// R5 structure: BK=32, 16 KB LDS, 3+ blocks/CU. Measured equivalents:
// BK=64/32KB (R9) and tap-shift/52KB (R7) all land 64-71 us — this variant
// has the best single measurement (64.4) and smallest FETCH. MfmaUtil ~33%
// is this structure's fixed point (m97 plateau); do not trade occupancy.
__global__ void conv_gemm_pool(const __hip_bfloat16* __restrict__ embp,
                               const __hip_bfloat16* __restrict__ posp,
                               const __hip_bfloat16* __restrict__ wce,
                               const __hip_bfloat16* __restrict__ wcp,
                               const float* __restrict__ corr,
                               unsigned* __restrict__ pooled) {
    __shared__ __hip_bfloat16 sA[128 * 32];
    __shared__ __hip_bfloat16 sB[128 * 32];

    const int tid  = threadIdx.x;
    const int wave = tid >> 6;
    const int lane = tid & 63;
    const int mt = blockIdx.x;
    const int nt = blockIdx.y;
    const int b  = mt >> 2;
    const int l0 = (mt & 3) * 128;
    const int n0 = nt * 128;

    const int wr = (wave & 1) * 64;
    const int wc = (wave >> 1) * 64;
    const int m  = lane & 15;
    const int q  = lane >> 4;

    f32x4 acc[4][4];
#pragma unroll
    for (int i = 0; i < 4; i++)
#pragma unroll
        for (int j = 0; j < 4; j++) acc[i][j] = (f32x4){0.f, 0.f, 0.f, 0.f};

    const int rowA = tid >> 2;
    const int cswz = (((tid & 3) ^ ((tid >> 3) & 3))) * 16;
    const int rsw  = (q ^ ((m >> 1) & 3)) * 16;

    auto step = [&](const char* Ab, int AsB, const char* Bb, int BsB) {
        cp16(Ab + rowA * AsB + cswz, (char*)sA + tid * 16);
        cp16(Bb + rowA * BsB + cswz, (char*)sB + tid * 16);
        cp16(Ab + (rowA + 64) * AsB + cswz, (char*)sA + (tid + 256) * 16);
        cp16(Bb + (rowA + 64) * BsB + cswz, (char*)sB + (tid + 256) * 16);
        __syncthreads();
        bf16x8 af[4], bfr[4];
#pragma unroll
        for (int i = 0; i < 4; i++)
            af[i] = *(const bf16x8*)((const char*)sA + (wr + i * 16 + m) * 64 + rsw);
#pragma unroll
        for (int j = 0; j < 4; j++)
            bfr[j] = *(const bf16x8*)((const char*)sB + (wc + j * 16 + m) * 64 + rsw);
#pragma unroll
        for (int i = 0; i < 4; i++)
#pragma unroll
            for (int j = 0; j < 4; j++)
                acc[i][j] = __builtin_amdgcn_mfma_f32_16x16x32_bf16(
                    af[i], bfr[j], acc[i][j], 0, 0, 0);
        __syncthreads();
    };

    for (int t = 0; t < 5; t++) {
        const char* Abase = (const char*)(embp + (size_t)(b * LE + l0 + t) * E_);
        const char* Bbase = (const char*)(wce + (size_t)(t * KOUT + n0) * E_);
        for (int kc = 0; kc < E_; kc += 32)
            step(Abase + kc * 2, E_ * 2, Bbase + kc * 2, E_ * 2);
    }
    for (int t = 0; t < 3; t++) {
        const char* Abase = (const char*)(posp + (size_t)(b * LPP + l0 + t) * 128);
        const char* Bbase = (const char*)(wcp + (size_t)(t * KOUT + n0) * 128);
        for (int kc = 0; kc < 128; kc += 32)
            step(Abase + kc * 2, 256, Bbase + kc * 2, 256);
    }

    const float* corrb = corr + b * 2 * KOUT;
#pragma unroll
    for (int j = 0; j < 4; j++) {
        int col = n0 + wc + j * 16 + m;
        float mx = -3.4e38f;
#pragma unroll
        for (int i = 0; i < 4; i++)
#pragma unroll
            for (int r = 0; r < 4; r++) {
                float v = acc[i][j][r];
                int l = l0 + wr + i * 16 + q * 4 + r;
                if (l == 0)      v -= corrb[col];
                if (l == L_ - 1) v -= corrb[KOUT + col];
                mx = fmaxf(mx, v);
            }
        mx = fmaxf(mx, __shfl_xor(mx, 16, 64));
        mx = fmaxf(mx, __shfl_xor(mx, 32, 64));
        if (q == 0) atomicMax(&pooled[b * KOUT + col], enc_f(mx));
    }
}

// ---------------------------------------------------------------------------
__global__ void lin1_k(const unsigned* __restrict__ pooled,
                       const float* __restrict__ conv_b,
                       const float* __restrict__ lin1_w,
                       const float* __restrict__ lin1_b,
                       float* __restrict__ com) {
    int bid = blockIdx.x;
    int wave = threadIdx.x >> 6, lane = threadIdx.x & 63;
    int b = bid >> 7;
    int h = (bid & 127) * 4 + wave;
    const float* w = lin1_w + (size_t)h * KOUT;
    const unsigned* pb = pooled + b * KOUT;
    float s = 0.f;
#pragma unroll
    for (int i = 0; i < 8; i++) {
        int k = lane + 64 * i;
        s += (dec_f(pb[k]) + conv_b[k]) * w[k];
    }
#pragma unroll
    for (int off = 32; off > 0; off >>= 1) s += __shfl_down(s, off, 64);
    if (lane == 0) com[(size_t)b * COMW + 1536 + h] = tanhf(s + lin1_b[h]);
}

__global__ void lin2_k(const float* __restrict__ com,
                       const float* __restrict__ lin2_w,
                       const float* __restrict__ lin2_b,
                       float* __restrict__ out) {
    int b = blockIdx.x;
    int wave = threadIdx.x >> 6, lane = threadIdx.x & 63;
    int t = blockIdx.y * 4 + wave;
    if (t >= T_) return;
    const float* w = lin2_w + (size_t)t * COMW;
    const float* c = com + (size_t)b * COMW;
    float s = 0.f;
#pragma unroll
    for (int i = 0; i < 32; i++) {
        int k = lane + 64 * i;
        s += c[k] * w[k];
    }
#pragma unroll
    for (int off = 32; off > 0; off >>= 1) s += __shfl_down(s, off, 64);
    if (lane == 0) out[b * T_ + t] = s + lin2_b[t];
}

// ---------------------------------------------------------------------------
extern "C" void kernel_launch(void* const* d_in, const int* in_sizes, int n_in,
                              void* d_out, int out_size, void* d_ws, size_t ws_size,
                              hipStream_t stream) {
    const int*   context = (const int*)d_in[0];
    const int*   sidx    = (const int*)d_in[1];
    const int*   oidx    = (const int*)d_in[2];
    const int*   sdis    = (const int*)d_in[3];
    const int*   odis    = (const int*)d_in[4];
    const float* etab    = (const float*)d_in[5];
    const float* ptab    = (const float*)d_in[6];
    const float* conv_w  = (const float*)d_in[7];
    const float* conv_b  = (const float*)d_in[8];
    const float* lin1_w  = (const float*)d_in[9];
    const float* lin1_b  = (const float*)d_in[10];
    const float* lin2_w  = (const float*)d_in[11];
    const float* lin2_b  = (const float*)d_in[12];
    float* out = (float*)d_out;

    char* ws = (char*)d_ws;
    size_t off = 0;
    __hip_bfloat16* embp = (__hip_bfloat16*)(ws + off);
    off += (size_t)B_ * LE * E_ * 2;             // 16.9 MB
    off = (off + 255) & ~(size_t)255;
    __hip_bfloat16* posp = (__hip_bfloat16*)(ws + off);
    off += (size_t)B_ * LPP * 128 * 2;           // 8.4 MB
    off = (off + 255) & ~(size_t)255;
    __hip_bfloat16* wce = (__hip_bfloat16*)(ws + off);
    off += (size_t)5 * KOUT * E_ * 2;            // 1.3 MB
    off = (off + 255) & ~(size_t)255;
    __hip_bfloat16* wcp = (__hip_bfloat16*)(ws + off);
    off += (size_t)3 * KOUT * 128 * 2;           // 0.4 MB
    off = (off + 255) & ~(size_t)255;
    __hip_bfloat16* wcorr = (__hip_bfloat16*)(ws + off);
    off += (size_t)2 * KOUT * E_ * 2;            // 0.5 MB
    off = (off + 255) & ~(size_t)255;
    float* corr = (float*)(ws + off);
    off += (size_t)B_ * 2 * KOUT * 4;            // 256 KB
    off = (off + 255) & ~(size_t)255;
    unsigned* pooled = (unsigned*)(ws + off);
    off += (size_t)B_ * KOUT * 4;                // 128 KB
    off = (off + 255) & ~(size_t)255;
    float* com = (float*)(ws + off);
    off += (size_t)B_ * COMW * 4;                // 512 KB

    prep<<<dim3(SEC_END), dim3(256), 0, stream>>>(
        conv_w, context, sidx, oidx, sdis, odis, etab, ptab,
        wce, wcp, wcorr, embp, posp, com, pooled);
    corr_k<<<dim3(4096), dim3(256), 0, stream>>>(context, etab, wcorr, corr);
    conv_gemm_pool<<<dim3(256, 4), dim3(256), 0, stream>>>(embp, posp, wce, wcp, corr, pooled);
    lin1_k<<<dim3(8192), dim3(256), 0, stream>>>(pooled, conv_b, lin1_w, lin1_b, com);
    lin2_k<<<dim3(B_, 14), dim3(256), 0, stream>>>(com, lin2_w, lin2_b, out);
}

// Round 11
// 189.231 us; speedup vs baseline: 1.1627x; 1.1299x over previous
//
#include <hip/hip_runtime.h>
#include <hip/hip_bf16.h>
#include <hip/hip_fp8.h>
#include <stdint.h>

#define B_   64
#define L_   512
#define E_   256
#define P_   64
#define KOUT 512
#define KS_  3
#define H_   512
#define T_   53
#define CINW 2688           // conv_w inner: 896*3
#define LE   516            // embp rows/batch: L + 4 (2 zero each side)
#define LPP  514            // posp rows/batch: L + 2 (1 zero each side)
#define COMW 2048           // 1536 ent + 512 sent_h

// fp8 uniform scaling: data x64, weights x64, accumulator /4096
#define FP8_S    64.0f
#define DESCALE  (1.0f / 4096.0f)

// prep-kernel grid sections
#define SEC_CW    0
#define SEC_EMBP  512
#define SEC_POSP  (SEC_EMBP + (B_ * LE / 4))     // 512 + 8256 = 8768
#define SEC_ENT   (SEC_POSP + (B_ * LPP / 4))    // 8768 + 8224 = 16992
#define SEC_POOL  (SEC_ENT + 2 * B_)             // 16992 + 128 = 17120
#define SEC_END   (SEC_POOL + 32)                // 17152

typedef __attribute__((ext_vector_type(4))) float f32x4;

__device__ __forceinline__ unsigned enc_f(float x) {
    unsigned u = __float_as_uint(x);
    return (u & 0x80000000u) ? ~u : (u | 0x80000000u);
}
__device__ __forceinline__ float dec_f(unsigned e) {
    return __uint_as_float((e & 0x80000000u) ? (e & 0x7fffffffu) : ~e);
}
__device__ __forceinline__ unsigned char f8c(float x) {
    __hip_fp8_e4m3 t(x);            // OCP e4m3fn (gfx950) — NOT fnuz
    return t.__x;
}

__device__ __forceinline__ void cp16(const void* g, void* l) {
    __builtin_amdgcn_global_load_lds(
        (const __attribute__((address_space(1))) unsigned int*)g,
        (__attribute__((address_space(3))) unsigned int*)l,
        16, 0, 0);
}

// ---------------------------------------------------------------------------
// Fused prep: 5 independent jobs selected by blockIdx.x section.
__global__ void prep(const float* __restrict__ conv_w,
                     const int* __restrict__ context,
                     const int* __restrict__ sidx,
                     const int* __restrict__ oidx,
                     const int* __restrict__ sdis,
                     const int* __restrict__ odis,
                     const float* __restrict__ etab,
                     const float* __restrict__ ptab,
                     unsigned char* __restrict__ wce,     // fp8, x64
                     unsigned char* __restrict__ wcp,     // fp8, x64
                     __hip_bfloat16* __restrict__ wcorr,  // bf16, exact path
                     unsigned char* __restrict__ embp,    // fp8, x64
                     unsigned char* __restrict__ posp,    // fp8, x64
                     float* __restrict__ com,
                     unsigned* __restrict__ pooled) {
    __shared__ float w[CINW];
    const int blk = blockIdx.x;
    const int tid = threadIdx.x;

    if (blk < SEC_EMBP) {
        // ---- combine_w: one block per output channel n ----
        int n = blk;
        const float* src = conv_w + (size_t)n * CINW;
        for (int i = tid; i < CINW; i += 256) w[i] = src[i];
        __syncthreads();
        for (int i = tid; i < 5 * E_; i += 256) {
            int d = i >> 8, c = i & 255;
            float s = 0.f;
#pragma unroll
            for (int tau = 0; tau <= 2; tau++) {
                int seg = d - tau;
                if (seg >= 0 && seg <= 2) s += w[(seg * 256 + c) * 3 + tau];
            }
            wce[((size_t)d * KOUT + n) * E_ + c] = f8c(s * FP8_S);
        }
        for (int i = tid; i < 3 * 128; i += 256) {
            int tau = i >> 7, p = i & 127;
            wcp[((size_t)tau * KOUT + n) * 128 + p] = f8c(w[(768 + p) * 3 + tau] * FP8_S);
        }
        for (int i = tid; i < 2 * E_; i += 256) {
            int which = i >> 8, c = i & 255;
            wcorr[((size_t)which * KOUT + n) * E_ + c] =
                __float2bfloat16(which ? w[c * 3 + 2] : w[(512 + c) * 3 + 0]);
        }
    } else if (blk < SEC_POSP) {
        // ---- build_embp (fp8 x64) ----
        int row = (blk - SEC_EMBP) * 4 + (tid >> 6);
        int lane = tid & 63;
        int b = row / LE, r = row % LE;
        unsigned char* out = embp + (size_t)row * E_;
        if (r < 2 || r >= LE - 2) {
            *(uchar4*)(out + lane * 4) = (uchar4){0, 0, 0, 0};
            return;
        }
        int token = context[b * L_ + (r - 2)];
        float4 v = *(const float4*)(etab + (size_t)token * E_ + lane * 4);
        uchar4 pk;
        pk.x = f8c(v.x * FP8_S); pk.y = f8c(v.y * FP8_S);
        pk.z = f8c(v.z * FP8_S); pk.w = f8c(v.w * FP8_S);
        *(uchar4*)(out + lane * 4) = pk;
    } else if (blk < SEC_ENT) {
        // ---- build_posp (fp8 x64) ----
        int row = (blk - SEC_POSP) * 4 + (tid >> 6);
        int lane = tid & 63;
        int b = row / LPP, r = row % LPP;
        unsigned char* out = posp + (size_t)row * 128;
        if (r < 1 || r >= LPP - 1) {
            *(unsigned short*)(out + lane * 2) = 0;
            return;
        }
        int l = r - 1;
        int which = lane >> 5;
        int i2 = (lane & 31) * 2;
        int t = which ? odis[b * L_ + l] : sdis[b * L_ + l];
        float2 v = *(const float2*)(ptab + (size_t)t * P_ + i2);
        unsigned short pk = (unsigned short)f8c(v.x * FP8_S)
                          | ((unsigned short)f8c(v.y * FP8_S) << 8);
        *(unsigned short*)(out + which * 64 + i2) = pk;
    } else if (blk < SEC_POOL) {
        // ---- entity_feats (fp32 exact) ----
        int idx = blk - SEC_ENT;
        int b = idx >> 1, which = idx & 1;
        const int* sp = which ? oidx : sidx;
        int s = sp[b * 2 + 0], e = sp[b * 2 + 1];
        const int* ctx = context + b * L_;
        float* outb = com + (size_t)b * COMW + which * 768;
        int d = tid;
        float sum = 0.f;
        for (int x = s; x <= e; ++x) sum += etab[(size_t)ctx[x] * E_ + d];
        outb[d] = sum / (float)(e - s + 1);
        outb[256 + d] = etab[(size_t)ctx[s - 1] * E_ + d];
        float r = 0.f;
        if (e + 1 < L_) r = etab[(size_t)ctx[e + 1] * E_ + d];
        outb[512 + d] = r;
    } else {
        // ---- zero pooled ----
        int base = ((blk - SEC_POOL) * 256 + tid) * 4;
        *(uint4*)(pooled + base) = (uint4){0, 0, 0, 0};
    }
}

// ---------------------------------------------------------------------------
// Edge-correction (fp32-exact): corr[b][which][n] = emb_edge . wcorr[which][n]
__global__ void corr_k(const int* __restrict__ ctx,
                       const float* __restrict__ etab,
                       const __hip_bfloat16* __restrict__ wcorr,
                       float* __restrict__ corr) {
    int wid = blockIdx.x * 4 + (threadIdx.x >> 6);
    int lane = threadIdx.x & 63;
    int n4    = wid & 127;
    int which = (wid >> 7) & 1;
    int b     = wid >> 8;
    int token = ctx[b * L_ + (which ? L_ - 1 : 0)];
    float4 ev = *(const float4*)(etab + (size_t)token * E_ + lane * 4);
#pragma unroll
    for (int k = 0; k < 4; k++) {
        int n = n4 * 4 + k;
        const __hip_bfloat16* wr = wcorr + ((size_t)which * KOUT + n) * E_ + lane * 4;
        float s = ev.x * __bfloat162float(wr[0]) + ev.y * __bfloat162float(wr[1])
                + ev.z * __bfloat162float(wr[2]) + ev.w * __bfloat162float(wr[3]);
#pragma unroll
        for (int off = 32; off > 0; off >>= 1) s += __shfl_down(s, off, 64);
        if (lane == 0) corr[(b * 2 + which) * KOUT + n] = s;
    }
}

// ---------------------------------------------------------------------------
// fp8 conv GEMM + fused maxpool + edge corr. R5 skeleton: 16 KB LDS (occupancy
// preserved), same staging-order/XOR-swizzle family (0 conflicts measured).
// Rows are 64 B = 64 fp8 elems (K=64/chunk -> 26 barrier pairs vs 52 in bf16);
// MFMA = mfma_f32_16x16x32_fp8_fp8 (i64 frags, lane k-map = q*8+j as in the
// verified bf16 K=32 shape). acc is x4096 (uniform fp8 scaling), descaled in
// the epilogue before corr-subtract and pooling.
__global__ void conv_gemm_pool(const unsigned char* __restrict__ embp,
                               const unsigned char* __restrict__ posp,
                               const unsigned char* __restrict__ wce,
                               const unsigned char* __restrict__ wcp,
                               const float* __restrict__ corr,
                               unsigned* __restrict__ pooled) {
    __shared__ unsigned char sA[128 * 64];   // 8 KB: 128 rows x 64B (64 fp8 K)
    __shared__ unsigned char sB[128 * 64];   // 8 KB

    const int tid  = threadIdx.x;
    const int wave = tid >> 6;
    const int lane = tid & 63;
    const int mt = blockIdx.x;
    const int nt = blockIdx.y;
    const int b  = mt >> 2;
    const int l0 = (mt & 3) * 128;
    const int n0 = nt * 128;

    const int wr = (wave & 1) * 64;
    const int wc = (wave >> 1) * 64;
    const int m  = lane & 15;
    const int q  = lane >> 4;

    f32x4 acc[4][4];
#pragma unroll
    for (int i = 0; i < 4; i++)
#pragma unroll
        for (int j = 0; j < 4; j++) acc[i][j] = (f32x4){0.f, 0.f, 0.f, 0.f};

    const int rowA = tid >> 2;                         // staging row (0..63, +64)
    const int cswz = ((tid & 3) ^ ((tid >> 3) & 3)) * 16;  // 16B-chunk XOR swizzle

    auto step = [&](const char* Ab, int AsB, const char* Bb, int BsB) {
        cp16(Ab + rowA * AsB + cswz, (char*)sA + tid * 16);
        cp16(Bb + rowA * BsB + cswz, (char*)sB + tid * 16);
        cp16(Ab + (rowA + 64) * AsB + cswz, (char*)sA + (tid + 256) * 16);
        cp16(Bb + (rowA + 64) * BsB + cswz, (char*)sB + (tid + 256) * 16);
        __syncthreads();
#pragma unroll
        for (int h = 0; h < 2; h++) {                  // two K=32 halves of the 64B row
            long af[4], bfr[4];
#pragma unroll
            for (int i = 0; i < 4; i++) {
                int row = wr + i * 16 + m;
                int pc = ((h << 1) | (q >> 1)) ^ ((row >> 1) & 3);
                af[i] = *(const long*)((const char*)sA + row * 64 + pc * 16 + (q & 1) * 8);
            }
#pragma unroll
            for (int j = 0; j < 4; j++) {
                int row = wc + j * 16 + m;
                int pc = ((h << 1) | (q >> 1)) ^ ((row >> 1) & 3);
                bfr[j] = *(const long*)((const char*)sB + row * 64 + pc * 16 + (q & 1) * 8);
            }
#pragma unroll
            for (int i = 0; i < 4; i++)
#pragma unroll
                for (int j = 0; j < 4; j++)
                    acc[i][j] = __builtin_amdgcn_mfma_f32_16x16x32_fp8_fp8(
                        af[i], bfr[j], acc[i][j], 0, 0, 0);
        }
        __syncthreads();
    };

    // emb phase: 5 taps x 4 chunks of 64 fp8 elems
    for (int t = 0; t < 5; t++) {
        const char* Abase = (const char*)(embp + (size_t)(b * LE + l0 + t) * E_);
        const char* Bbase = (const char*)(wce + (size_t)(t * KOUT + n0) * E_);
        for (int kc = 0; kc < E_; kc += 64)
            step(Abase + kc, E_, Bbase + kc, E_);
    }
    // pos phase: 3 taps x 2 chunks
    for (int t = 0; t < 3; t++) {
        const char* Abase = (const char*)(posp + (size_t)(b * LPP + l0 + t) * 128);
        const char* Bbase = (const char*)(wcp + (size_t)(t * KOUT + n0) * 128);
        for (int kc = 0; kc < 128; kc += 64)
            step(Abase + kc, 128, Bbase + kc, 128);
    }

    const float* corrb = corr + b * 2 * KOUT;
#pragma unroll
    for (int j = 0; j < 4; j++) {
        int col = n0 + wc + j * 16 + m;
        float mx = -3.4e38f;
#pragma unroll
        for (int i = 0; i < 4; i++)
#pragma unroll
            for (int r = 0; r < 4; r++) {
                float v = acc[i][j][r] * DESCALE;
                int l = l0 + wr + i * 16 + q * 4 + r;
                if (l == 0)      v -= corrb[col];
                if (l == L_ - 1) v -= corrb[KOUT + col];
                mx = fmaxf(mx, v);
            }
        mx = fmaxf(mx, __shfl_xor(mx, 16, 64));
        mx = fmaxf(mx, __shfl_xor(mx, 32, 64));
        if (q == 0) atomicMax(&pooled[b * KOUT + col], enc_f(mx));
    }
}

// ---------------------------------------------------------------------------
__global__ void lin1_k(const unsigned* __restrict__ pooled,
                       const float* __restrict__ conv_b,
                       const float* __restrict__ lin1_w,
                       const float* __restrict__ lin1_b,
                       float* __restrict__ com) {
    int bid = blockIdx.x;
    int wave = threadIdx.x >> 6, lane = threadIdx.x & 63;
    int b = bid >> 7;
    int h = (bid & 127) * 4 + wave;
    const float* w = lin1_w + (size_t)h * KOUT;
    const unsigned* pb = pooled + b * KOUT;
    float s = 0.f;
#pragma unroll
    for (int i = 0; i < 8; i++) {
        int k = lane + 64 * i;
        s += (dec_f(pb[k]) + conv_b[k]) * w[k];
    }
#pragma unroll
    for (int off = 32; off > 0; off >>= 1) s += __shfl_down(s, off, 64);
    if (lane == 0) com[(size_t)b * COMW + 1536 + h] = tanhf(s + lin1_b[h]);
}

__global__ void lin2_k(const float* __restrict__ com,
                       const float* __restrict__ lin2_w,
                       const float* __restrict__ lin2_b,
                       float* __restrict__ out) {
    int b = blockIdx.x;
    int wave = threadIdx.x >> 6, lane = threadIdx.x & 63;
    int t = blockIdx.y * 4 + wave;
    if (t >= T_) return;
    const float* w = lin2_w + (size_t)t * COMW;
    const float* c = com + (size_t)b * COMW;
    float s = 0.f;
#pragma unroll
    for (int i = 0; i < 32; i++) {
        int k = lane + 64 * i;
        s += c[k] * w[k];
    }
#pragma unroll
    for (int off = 32; off > 0; off >>= 1) s += __shfl_down(s, off, 64);
    if (lane == 0) out[b * T_ + t] = s + lin2_b[t];
}

// ---------------------------------------------------------------------------
extern "C" void kernel_launch(void* const* d_in, const int* in_sizes, int n_in,
                              void* d_out, int out_size, void* d_ws, size_t ws_size,
                              hipStream_t stream) {
    const int*   context = (const int*)d_in[0];
    const int*   sidx    = (const int*)d_in[1];
    const int*   oidx    = (const int*)d_in[2];
    const int*   sdis    = (const int*)d_in[3];
    const int*   odis    = (const int*)d_in[4];
    const float* etab    = (const float*)d_in[5];
    const float* ptab    = (const float*)d_in[6];
    const float* conv_w  = (const float*)d_in[7];
    const float* conv_b  = (const float*)d_in[8];
    const float* lin1_w  = (const float*)d_in[9];
    const float* lin1_b  = (const float*)d_in[10];
    const float* lin2_w  = (const float*)d_in[11];
    const float* lin2_b  = (const float*)d_in[12];
    float* out = (float*)d_out;

    char* ws = (char*)d_ws;
    size_t off = 0;
    unsigned char* embp = (unsigned char*)(ws + off);
    off += (size_t)B_ * LE * E_;                 // 8.45 MB (fp8)
    off = (off + 255) & ~(size_t)255;
    unsigned char* posp = (unsigned char*)(ws + off);
    off += (size_t)B_ * LPP * 128;               // 4.2 MB (fp8)
    off = (off + 255) & ~(size_t)255;
    unsigned char* wce = (unsigned char*)(ws + off);
    off += (size_t)5 * KOUT * E_;                // 655 KB (fp8)
    off = (off + 255) & ~(size_t)255;
    unsigned char* wcp = (unsigned char*)(ws + off);
    off += (size_t)3 * KOUT * 128;               // 197 KB (fp8)
    off = (off + 255) & ~(size_t)255;
    __hip_bfloat16* wcorr = (__hip_bfloat16*)(ws + off);
    off += (size_t)2 * KOUT * E_ * 2;            // 0.5 MB
    off = (off + 255) & ~(size_t)255;
    float* corr = (float*)(ws + off);
    off += (size_t)B_ * 2 * KOUT * 4;            // 256 KB
    off = (off + 255) & ~(size_t)255;
    unsigned* pooled = (unsigned*)(ws + off);
    off += (size_t)B_ * KOUT * 4;                // 128 KB
    off = (off + 255) & ~(size_t)255;
    float* com = (float*)(ws + off);
    off += (size_t)B_ * COMW * 4;                // 512 KB

    prep<<<dim3(SEC_END), dim3(256), 0, stream>>>(
        conv_w, context, sidx, oidx, sdis, odis, etab, ptab,
        wce, wcp, wcorr, embp, posp, com, pooled);
    corr_k<<<dim3(4096), dim3(256), 0, stream>>>(context, etab, wcorr, corr);
    conv_gemm_pool<<<dim3(256, 4), dim3(256), 0, stream>>>(embp, posp, wce, wcp, corr, pooled);
    lin1_k<<<dim3(8192), dim3(256), 0, stream>>>(pooled, conv_b, lin1_w, lin1_b, com);
    lin2_k<<<dim3(B_, 14), dim3(256), 0, stream>>>(com, lin2_w, lin2_b, out);
}